// Round 3
// baseline (460.830 us; speedup 1.0000x reference)
//
#include <hip/hip_runtime.h>
#include <math.h>

typedef __attribute__((ext_vector_type(8))) short bf16x8;
typedef __attribute__((ext_vector_type(4))) float f32x4;
typedef unsigned short u16;
typedef unsigned int u32;

#define N_TOK 4096
#define HID   2048
#define N_HEAD 16
#define HDIM  128
#define QK_SCALE 0.08838834764831845f /* 128^-0.5 */
#define LOG2E_   1.4426950408889634f

__device__ __forceinline__ u16 f2bf(float x) {
  union { float f; u32 u; } v; v.f = x;
  u32 r = v.u + 0x7fffu + ((v.u >> 16) & 1u);
  return (u16)(r >> 16);
}

__device__ __forceinline__ u32 cvtpk(float lo, float hi) {
  u32 r;
  asm("v_cvt_pk_bf16_f32 %0, %1, %2" : "=v"(r) : "v"(lo), "v"(hi));
  return r;
}

__device__ __forceinline__ void async16(const void* g, void* l) {
  __builtin_amdgcn_global_load_lds(
      (const __attribute__((address_space(1))) void*)g,
      (__attribute__((address_space(3))) void*)l, 16, 0, 0);
}

#define MFMA(a, b, c) __builtin_amdgcn_mfma_f32_16x16x32_bf16((a), (b), (c), 0, 0, 0)

// ---------------- rope tables ----------------
__global__ void k_rope(float* __restrict__ cosT, float* __restrict__ sinT) {
  int l = blockIdx.x;
  int p = threadIdx.x;
  int c1 = l >> 10, c2 = (l >> 5) & 31, c3 = l & 31;
  int pos, j; float dim;
  if (p < 8)       { pos = c1; j = p;      dim = 16.f; }
  else if (p < 36) { pos = c2; j = p - 8;  dim = 56.f; }
  else             { pos = c3; j = p - 36; dim = 56.f; }
  float freq = exp2f(-8.0f * (2.0f * (float)j) / dim);
  float ang = (float)pos * freq;
  float s, c;
  sincosf(ang, &s, &c);
  cosT[l * 64 + p] = c;
  sinT[l * 64 + p] = s;
}

// ---------------- convert X fp32 -> bf16 ----------------
__global__ __launch_bounds__(256) void k_cvt_x(const float* __restrict__ X, u16* __restrict__ Xb) {
  int i = blockIdx.x * 256 + threadIdx.x;
  float4 v = ((const float4*)X)[i];
  ushort4 o;
  o.x = f2bf(v.x); o.y = f2bf(v.y); o.z = f2bf(v.z); o.w = f2bf(v.w);
  ((ushort4*)Xb)[i] = o;
}

// ---------------- transpose+convert W: WT[z][n][k] = bf16(W[k][n]), z = q,k,v,o ----------------
__global__ __launch_bounds__(256) void k_tw(const float* __restrict__ Wq, const float* __restrict__ Wk,
                                            const float* __restrict__ Wv, const float* __restrict__ Wo,
                                            u16* __restrict__ WT) {
  int z = blockIdx.z;
  const float* W = (z == 0) ? Wq : (z == 1) ? Wk : (z == 2) ? Wv : Wo;
  u16* dst = WT + (size_t)z * 2048 * 2048;
  __shared__ __align__(16) float T[64][69];
  int n0 = blockIdx.x * 64, k0 = blockIdx.y * 64;
  int tid = threadIdx.x;
  int r = tid >> 4, c4 = tid & 15;
#pragma unroll
  for (int i = 0; i < 4; ++i) {
    int row = r + i * 16;
    float4 v = *(const float4*)(W + (size_t)(k0 + row) * 2048 + n0 + c4 * 4);
    T[row][c4 * 4 + 0] = v.x; T[row][c4 * 4 + 1] = v.y;
    T[row][c4 * 4 + 2] = v.z; T[row][c4 * 4 + 3] = v.w;
  }
  __syncthreads();
#pragma unroll
  for (int i = 0; i < 4; ++i) {
    int row = r + i * 16;
    ushort4 o;
    o.x = f2bf(T[c4 * 4 + 0][row]);
    o.y = f2bf(T[c4 * 4 + 1][row]);
    o.z = f2bf(T[c4 * 4 + 2][row]);
    o.w = f2bf(T[c4 * 4 + 3][row]);
    *(ushort4*)(dst + (size_t)(n0 + row) * 2048 + k0 + c4 * 4) = o;
  }
}

// ================= 8-phase 256x256 GEMM (T2+T3+T4+T5) =================
// C[M=4096, Ntot] = A[M,K]*Bt[Ntot,K]^T + bias(col). 512 thr, 8 waves (2M x 4N),
// per-wave 128x64 out split across LDS halves. One 16KB half-unit staged per phase,
// counted vmcnt at phases 1/2/5/6; raw barriers only. A-fragments reused across
// phase pairs that share an A-half (READA=1 on odd phases only).

#define VM8 asm volatile("s_waitcnt vmcnt(8)" ::: "memory");
#define VM6 asm volatile("s_waitcnt vmcnt(6)" ::: "memory");
#define VMNONE

#define STAGEU(SB, SAB, SH, ST) do {                                            \
    int st_ = (ST) < Tk ? (ST) : Tk - 1;                                        \
    const char* src_ = ((SAB) ? Bp : Ap) + (size_t)((SH) * 128) * Kb + (size_t)st_ * 128; \
    char* dstl_ = &Lds[SB][SAB][SH][0];                                         \
    _Pragma("unroll")                                                           \
    for (int i_ = 0; i_ < 2; ++i_) {                                            \
      int flat_ = tid + 512 * i_;                                               \
      int row_ = flat_ >> 3, sb_ = flat_ & 7;                                   \
      async16(src_ + (size_t)row_ * Kb + ((sb_ ^ (row_ & 7)) << 4), dstl_ + flat_ * 16); \
    }                                                                           \
  } while (0)

#define PHASE(BUF, MH, NH, READA, VMOP, SB, SAB, SH, ST) do {                   \
    VMOP                                                                        \
    __builtin_amdgcn_s_barrier();                                               \
    asm volatile("" ::: "memory");                                              \
    bf16x8 bb[2][2];                                                            \
    const char* Lm = &Lds[BUF][0][MH][0];                                       \
    const char* Ln = &Lds[BUF][1][NH][0];                                       \
    if (READA) {                                                                \
      _Pragma("unroll")                                                         \
      for (int kk = 0; kk < 2; ++kk)                                            \
        _Pragma("unroll")                                                       \
        for (int mf = 0; mf < 4; ++mf) {                                        \
          int row = wmIdx * 64 + mf * 16 + cl;                                  \
          af[kk][mf] = *(const bf16x8*)(Lm + row * 128 + (((kk * 4 + g) ^ (row & 7)) << 4)); \
        }                                                                       \
    }                                                                           \
    _Pragma("unroll")                                                           \
    for (int kk = 0; kk < 2; ++kk)                                              \
      _Pragma("unroll")                                                         \
      for (int nf = 0; nf < 2; ++nf) {                                          \
        int row = wnIdx * 32 + nf * 16 + cl;                                    \
        bb[kk][nf] = *(const bf16x8*)(Ln + row * 128 + (((kk * 4 + g) ^ (row & 7)) << 4)); \
      }                                                                         \
    STAGEU(SB, SAB, SH, ST);                                                    \
    __builtin_amdgcn_s_setprio(1);                                              \
    _Pragma("unroll")                                                           \
    for (int kk = 0; kk < 2; ++kk)                                              \
      _Pragma("unroll")                                                         \
      for (int mf = 0; mf < 4; ++mf)                                            \
        _Pragma("unroll")                                                       \
        for (int nf = 0; nf < 2; ++nf)                                          \
          acc[(MH) * 4 + mf][(NH) * 2 + nf] =                                   \
              MFMA(af[kk][mf], bb[kk][nf], acc[(MH) * 4 + mf][(NH) * 2 + nf]);  \
    __builtin_amdgcn_s_setprio(0);                                              \
  } while (0)

__global__ __launch_bounds__(512, 2) void k_gemm8(const u16* __restrict__ A, const u16* __restrict__ Bt,
                                                  const float* __restrict__ b0, const float* __restrict__ b1,
                                                  const float* __restrict__ b2, float* __restrict__ C,
                                                  int gn, int K, int ldc) {
  __shared__ __align__(16) char Lds[2][2][2][16384];  // [buf][A/B][half][128x64 bf16]
  int tid = threadIdx.x;
  int lane = tid & 63, wid = tid >> 6;
  int g = lane >> 4, cl = lane & 15;
  int wmIdx = wid >> 2, wnIdx = wid & 3;
  int nwg = gridDim.x;
  int wg = (int)blockIdx.x;
  int cpx = nwg >> 3;
  wg = (wg & 7) * cpx + (wg >> 3);  // XCD swizzle (nwg % 8 == 0 always here)
  int bm = wg / gn, bn = wg % gn;
  size_t Kb = (size_t)K * 2;
  const char* Ap = (const char*)A + (size_t)bm * 256 * Kb;
  const char* Bp = (const char*)Bt + (size_t)bn * 256 * Kb;
  int Tk = K >> 6;

  f32x4 acc[8][4] = {};
  bf16x8 af[2][4];

  // prologue: stage units in canonical stream order
  STAGEU(0, 0, 0, 0);  // A0(0)
  STAGEU(0, 1, 0, 0);  // B0(0)
  STAGEU(0, 0, 1, 0);  // A1(0)
  STAGEU(0, 1, 1, 0);  // B1(0)
  STAGEU(1, 0, 0, 1);  // A0(1)
  STAGEU(1, 1, 0, 1);  // B0(1)

  int nIter = Tk >> 1;
  for (int it = 0; it < nIter; ++it) {
    int t = 2 * it;
    PHASE(0, 0, 0, 1, VM8,    1, 0, 1, t + 1);  // stage A1(t+1) -> buf1
    PHASE(0, 0, 1, 0, VM6,    1, 1, 1, t + 1);  // B1(t+1) -> buf1
    PHASE(0, 1, 0, 1, VMNONE, 0, 0, 0, t + 2);  // A0(t+2) -> buf0
    PHASE(0, 1, 1, 0, VMNONE, 0, 1, 0, t + 2);  // B0(t+2) -> buf0
    PHASE(1, 0, 0, 1, VM8,    0, 0, 1, t + 2);  // A1(t+2) -> buf0
    PHASE(1, 0, 1, 0, VM6,    0, 1, 1, t + 2);  // B1(t+2) -> buf0
    PHASE(1, 1, 0, 1, VMNONE, 1, 0, 0, t + 3);  // A0(t+3) -> buf1
    PHASE(1, 1, 1, 0, VMNONE, 1, 1, 0, t + 3);  // B0(t+3) -> buf1
  }

  // epilogue
#pragma unroll
  for (int mfp = 0; mfp < 8; ++mfp) {
    int rowBase = (mfp < 4 ? wmIdx * 64 + mfp * 16 : 128 + wmIdx * 64 + (mfp - 4) * 16) + g * 4;
    int rowG = bm * 256 + rowBase;
#pragma unroll
    for (int nfp = 0; nfp < 4; ++nfp) {
      int colLoc = (nfp < 2 ? wnIdx * 32 + nfp * 16 : 128 + wnIdx * 32 + (nfp - 2) * 16) + cl;
      int col = bn * 256 + colLoc;
      int z = col >> 11;
      const float* bp = (z == 0) ? b0 : (z == 1) ? b1 : b2;
      float bv = bp[col & 2047];
#pragma unroll
      for (int rr = 0; rr < 4; ++rr)
        C[(size_t)(rowG + rr) * ldc + col] = acc[mfp][nfp][rr] + bv;
    }
  }
}

// ---------------- fused RMSNorm + RoPE + tile-layout write (Q or K) ----------------
__global__ __launch_bounds__(256) void k_prep_qk(const float* __restrict__ src, int stride,
                                                 const float* __restrict__ gg,
                                                 const float* __restrict__ cosT, const float* __restrict__ sinT,
                                                 u16* __restrict__ dst, int isk) {
  int job = blockIdx.x * 4 + (threadIdx.x >> 6);
  int lane = threadIdx.x & 63;
  int tok = job & 4095, h = job >> 12;
  const float* row = src + (size_t)tok * stride + h * 128;
  float2 x = *(const float2*)(row + lane * 2);
  float ss = x.x * x.x + x.y * x.y;
#pragma unroll
  for (int m = 1; m < 64; m <<= 1) ss += __shfl_xor(ss, m, 64);
  float rms = rsqrtf(ss * (1.0f / 128.0f) + 1e-6f);
  float x0 = x.x * rms * gg[lane * 2];
  float x1 = x.y * rms * gg[lane * 2 + 1];
  float c = cosT[tok * 64 + lane], s = sinT[tok * 64 + lane];
  float y0 = x0 * c - x1 * s;
  float y1 = x1 * c + x0 * s;
  if (!isk) { y0 *= QK_SCALE * LOG2E_; y1 *= QK_SCALE * LOG2E_; }
  u32 pk = cvtpk(y0, y1);
  int c1 = tok >> 10, c2 = (tok >> 5) & 31, c3 = tok & 31;
  int n = (c2 >> 3) * 4 + (c3 >> 3);
  int t = c1 * 64 + (c2 & 7) * 8 + (c3 & 7);
  size_t rowidx = (size_t)(h * 16 + n) * 256 + t;
  if (!isk) {
    ((u32*)dst)[rowidx * 64 + lane] = pk;
  } else {
    char* base = (char*)dst + rowidx * 256;
    *(u32*)(base + ((((lane >> 2) ^ (t & 7)) << 4) + (lane & 3) * 4)) = pk;
  }
}

// ---------------- V: convert + transpose, swizzle baked ----------------
__global__ __launch_bounds__(256) void k_prep_v(const float* __restrict__ src, int stride,
                                                u16* __restrict__ Vt) {
  __shared__ __align__(16) u16 T[128][72];
  int tid = threadIdx.x;
  int h = blockIdx.x >> 6, n = (blockIdx.x >> 2) & 15, ch = blockIdx.x & 3;
  int d2 = n >> 2, d3 = n & 3;
  int tc = tid >> 2, cq = tid & 3;
  int tok = (ch * 32 + d2 * 8 + (tc >> 3)) * 32 + d3 * 8 + (tc & 7);
  const float* sp = src + (size_t)tok * stride + h * 128;
#pragma unroll
  for (int i = 0; i < 8; ++i) {
    int d0 = cq * 4 + i * 16;
    float4 v = *(const float4*)(sp + d0);
    T[d0 + 0][tc] = f2bf(v.x); T[d0 + 1][tc] = f2bf(v.y);
    T[d0 + 2][tc] = f2bf(v.z); T[d0 + 3][tc] = f2bf(v.w);
  }
  __syncthreads();
  int d = tid >> 1, half = tid & 1;
  char* dstb = (char*)Vt + ((size_t)((h * 16 + n) * 4 + ch) * 128 + d) * 128;
#pragma unroll
  for (int b = 0; b < 4; ++b) {
    int blk = half * 4 + b;
    uint4 val = *(const uint4*)&T[d][blk * 8];
    *(uint4*)(dstb + ((blk ^ (d & 7)) << 4)) = val;
  }
}

// ---------------- sliding tiled attention (skip-max softmax) ----------------
__global__ __launch_bounds__(512) void k_attn(const u16* __restrict__ Qt, const u16* __restrict__ Kt,
                                              const u16* __restrict__ Vt, u16* __restrict__ AO) {
  __shared__ __align__(16) char Kl[2][16384];
  __shared__ __align__(16) char Vl[2][16384];
  __shared__ __align__(16) char Pl[8][4096];
  int tid = threadIdx.x;
  int lane = tid & 63, wid = tid >> 6;
  int g = lane >> 4, cl = lane & 15;
  // XCD swizzle: 2 heads per XCD so each XCD's L2 holds its heads' KV (4 MB)
  int bid = (int)blockIdx.x;
  int xcd = bid & 7, i = bid >> 3;
  int h = xcd * 2 + (i >> 4);
  int n = i & 15;
  int d2 = n >> 2, d3 = n & 3;
  int s2 = d2 - 1; s2 = s2 < 0 ? 0 : (s2 > 1 ? 1 : s2);
  int s3 = d3 - 1; s3 = s3 < 0 ? 0 : (s3 > 1 ? 1 : s3);
  int q0 = wid * 32;

  bf16x8 qf[2][4];
  const char* Qb = (const char*)Qt + (size_t)(h * 16 + n) * 256 * 256;
#pragma unroll
  for (int nq = 0; nq < 2; ++nq)
#pragma unroll
    for (int kf = 0; kf < 4; ++kf)
      qf[nq][kf] = *(const bf16x8*)(Qb + (q0 + nq * 16 + cl) * 256 + kf * 64 + g * 16);

  f32x4 o[2][8] = {};
  float L0 = 0.f, L1 = 0.f;  // per-lane partial softmax denominators (q = cl)

  auto stage = [&](int buf, int c) {
    int kvi = c >> 2, cc = c & 3;
    int i2 = kvi / 3, i3 = kvi - i2 * 3;
    int kvt = (s2 + i2) * 4 + (s3 + i3);
    const char* Kb = (const char*)Kt + ((size_t)((h * 16 + kvt) * 256 + cc * 64)) * 256;
    const char* Vb = (const char*)Vt + ((size_t)((h * 16 + kvt) * 4 + cc)) * 16384;
#pragma unroll
    for (int i_ = 0; i_ < 2; ++i_) {
      int flat = tid + 512 * i_;
      async16(Kb + flat * 16, &Kl[buf][0] + flat * 16);
      async16(Vb + flat * 16, &Vl[buf][0] + flat * 16);
    }
  };

  stage(0, 0);
  __syncthreads();

  char* Pw = &Pl[wid][0];
  for (int c = 0; c < 36; ++c) {
    int cur = c & 1;
    if (c + 1 < 36) stage(cur ^ 1, c + 1);
    const char* Kc = &Kl[cur][0];
    // S^T = K x Q
    f32x4 st[4][2] = {};
    __builtin_amdgcn_s_setprio(1);
#pragma unroll
    for (int ks = 0; ks < 4; ++ks) {
      bf16x8 af[4];
#pragma unroll
      for (int mk = 0; mk < 4; ++mk) {
        int row = mk * 16 + cl;
        af[mk] = *(const bf16x8*)(Kc + row * 256 + (((ks * 4 + g) ^ (row & 7)) << 4));
      }
#pragma unroll
      for (int mk = 0; mk < 4; ++mk) {
        st[mk][0] = MFMA(af[mk], qf[0][ks], st[mk][0]);
        st[mk][1] = MFMA(af[mk], qf[1][ks], st[mk][1]);
      }
    }
    __builtin_amdgcn_s_setprio(0);
    // p = exp2(st)  (no max subtraction: |st| <= 16.4 provably, fp32-safe)
#pragma unroll
    for (int mk = 0; mk < 4; ++mk)
#pragma unroll
      for (int r = 0; r < 4; ++r) {
        float p0 = exp2f(st[mk][0][r]);
        float p1 = exp2f(st[mk][1][r]);
        st[mk][0][r] = p0; L0 += p0;
        st[mk][1][r] = p1; L1 += p1;
      }
    // P -> per-wave LDS (bf16, swizzled)
#pragma unroll
    for (int nq = 0; nq < 2; ++nq) {
      int q = nq * 16 + cl;
#pragma unroll
      for (int mk = 0; mk < 4; ++mk)
#pragma unroll
        for (int rp = 0; rp < 2; ++rp) {
          u32 pk = cvtpk(st[mk][nq][rp * 2], st[mk][nq][rp * 2 + 1]);
          int kv = mk * 16 + g * 4 + rp * 2;
          *(u32*)(Pw + q * 128 + (((kv >> 3) ^ (q & 7)) << 4) + (kv & 7) * 2) = pk;
        }
    }
    // PV
    const char* Vc = &Vl[cur][0];
    __builtin_amdgcn_s_setprio(1);
#pragma unroll
    for (int ks = 0; ks < 2; ++ks) {
      bf16x8 pf0, pf1, vf[8];
      {
        int q = cl;
        pf0 = *(const bf16x8*)(Pw + q * 128 + (((ks * 4 + g) ^ (q & 7)) << 4));
        q = 16 + cl;
        pf1 = *(const bf16x8*)(Pw + q * 128 + (((ks * 4 + g) ^ (q & 7)) << 4));
      }
#pragma unroll
      for (int nd = 0; nd < 8; ++nd) {
        int d = nd * 16 + cl;
        vf[nd] = *(const bf16x8*)(Vc + d * 128 + (((ks * 4 + g) ^ (d & 7)) << 4));
      }
#pragma unroll
      for (int nd = 0; nd < 8; ++nd) {
        o[0][nd] = MFMA(pf0, vf[nd], o[0][nd]);
        o[1][nd] = MFMA(pf1, vf[nd], o[1][nd]);
      }
    }
    __builtin_amdgcn_s_setprio(0);
    __syncthreads();
  }
  // epilogue
  L0 += __shfl_xor(L0, 16, 64); L0 += __shfl_xor(L0, 32, 64);
  L1 += __shfl_xor(L1, 16, 64); L1 += __shfl_xor(L1, 32, 64);
  float lr0[4], lr1[4];
#pragma unroll
  for (int r = 0; r < 4; ++r) {
    lr0[r] = 1.0f / __shfl(L0, g * 4 + r, 64);
    lr1[r] = 1.0f / __shfl(L1, g * 4 + r, 64);
  }
#pragma unroll
  for (int mo = 0; mo < 2; ++mo)
#pragma unroll
    for (int r = 0; r < 4; ++r) {
      int t = q0 + mo * 16 + g * 4 + r;
      int t1 = t >> 6, t2 = (t >> 3) & 7, t3 = t & 7;
      int tok = (t1 * 32 + d2 * 8 + t2) * 32 + d3 * 8 + t3;
      u16* orow = AO + (size_t)tok * HID + h * HDIM;
      float lr = (mo == 0) ? lr0[r] : lr1[r];
#pragma unroll
      for (int nd = 0; nd < 8; ++nd)
        orow[nd * 16 + cl] = f2bf(o[mo][nd][r] * lr);
    }
}

// ---------------- launcher ----------------
extern "C" void kernel_launch(void* const* d_in, const int* in_sizes, int n_in,
                              void* d_out, int out_size, void* d_ws, size_t ws_size,
                              hipStream_t stream) {
  const float* X  = (const float*)d_in[0];
  const float* Wq = (const float*)d_in[1];
  const float* bq = (const float*)d_in[2];
  const float* Wk = (const float*)d_in[3];
  const float* bk = (const float*)d_in[4];
  const float* Wv = (const float*)d_in[5];
  const float* bv = (const float*)d_in[6];
  const float* Wo = (const float*)d_in[7];
  const float* bo = (const float*)d_in[8];
  const float* gq = (const float*)d_in[9];
  const float* gk = (const float*)d_in[10];

  char* ws = (char*)d_ws;
  size_t off = 0;
  auto alloc = [&](size_t bytes) { void* p = ws + off; off = (off + bytes + 255) & ~(size_t)255; return p; };

  u16*   Xb  = (u16*)alloc((size_t)N_TOK * HID * 2);
  u16*   WT  = (u16*)alloc((size_t)4 * 2048 * 2048 * 2);
  float* COS = (float*)alloc((size_t)N_TOK * 64 * 4);
  float* SIN = (float*)alloc((size_t)N_TOK * 64 * 4);
  u16*   Qt  = (u16*)alloc((size_t)N_TOK * HID * 2);
  u16*   Kt  = (u16*)alloc((size_t)N_TOK * HID * 2);
  u16*   Vt  = (u16*)alloc((size_t)N_TOK * HID * 2);
  u16*   AO  = (u16*)alloc((size_t)N_TOK * HID * 2);
  size_t fixed = off;
  // fused plan needs PF = 4096*6144*4 = 100.7 MB on top; fallback needs 33.6 MB
  size_t needF = fixed + (size_t)N_TOK * 6144 * 4 + 256;
  bool fused = (ws_size >= needF);
  float* PF = (float*)alloc(fused ? (size_t)N_TOK * 6144 * 4 : (size_t)N_TOK * 2048 * 4);
  float* OUT = (float*)d_out;

  k_rope<<<N_TOK, 64, 0, stream>>>(COS, SIN);
  k_cvt_x<<<(N_TOK * HID / 4) / 256, 256, 0, stream>>>(X, Xb);
  k_tw<<<dim3(32, 32, 4), 256, 0, stream>>>(Wq, Wk, Wv, Wo, WT);

  if (fused) {
    // one QKV GEMM: N = 6144 (WT has q,k,v contiguous)
    k_gemm8<<<16 * 24, 512, 0, stream>>>(Xb, WT, bq, bk, bv, PF, 24, 2048, 6144);
    k_prep_qk<<<16384, 256, 0, stream>>>(PF + 0,    6144, gq, COS, SIN, Qt, 0);
    k_prep_qk<<<16384, 256, 0, stream>>>(PF + 2048, 6144, gk, COS, SIN, Kt, 1);
    k_prep_v <<<1024,  256, 0, stream>>>(PF + 4096, 6144, Vt);
  } else {
    k_gemm8<<<16 * 8, 512, 0, stream>>>(Xb, WT + (size_t)0 * 2048 * 2048, bq, bq, bq, PF, 8, 2048, 2048);
    k_prep_qk<<<16384, 256, 0, stream>>>(PF, 2048, gq, COS, SIN, Qt, 0);
    k_gemm8<<<16 * 8, 512, 0, stream>>>(Xb, WT + (size_t)1 * 2048 * 2048, bk, bk, bk, PF, 8, 2048, 2048);
    k_prep_qk<<<16384, 256, 0, stream>>>(PF, 2048, gk, COS, SIN, Kt, 1);
    k_gemm8<<<16 * 8, 512, 0, stream>>>(Xb, WT + (size_t)2 * 2048 * 2048, bv, bv, bv, PF, 8, 2048, 2048);
    k_prep_v<<<1024, 256, 0, stream>>>(PF, 2048, Vt);
  }

  k_attn<<<256, 512, 0, stream>>>(Qt, Kt, Vt, AO);

  k_gemm8<<<16 * 8, 512, 0, stream>>>(AO, WT + (size_t)3 * 2048 * 2048, bo, bo, bo, OUT, 8, 2048, 2048);
}